// Round 2
// baseline (1010.693 us; speedup 1.0000x reference)
//
#include <hip/hip_runtime.h>
#include <math.h>

#define DDIM 1024
#define NH 16
#define HDIM 64
#define SCALE 0.125f
#define DLAM -0.1f
#define LNEPS 1e-5f
#define NS 32

__device__ inline float dot4(float4 a, float4 b) {
    return fmaf(a.x, b.x, fmaf(a.y, b.y, fmaf(a.z, b.z, a.w * b.w)));
}

// K1: q[b,c] = query[b,:] @ Wq[:,c] + bq[c]; grid (B, 8), 128 cols/block, 2-way d-split
__global__ __launch_bounds__(256) void k_q(const float* __restrict__ query,
                                           const float* __restrict__ Wq,
                                           const float* __restrict__ bq,
                                           float* __restrict__ qout) {
    int b = blockIdx.x, c0 = blockIdx.y * 128;
    __shared__ float qs[DDIM];
    __shared__ float ps[256];
    for (int i = threadIdx.x; i < DDIM; i += 256) qs[i] = query[b * DDIM + i];
    __syncthreads();
    int t = threadIdx.x;
    int col = c0 + (t & 127);
    int d0 = (t >> 7) * 512;
    float acc = 0.f;
    for (int d = d0; d < d0 + 512; ++d) acc = fmaf(qs[d], Wq[(size_t)d * DDIM + col], acc);
    ps[t] = acc;
    __syncthreads();
    if (t < 128) qout[b * DDIM + col] = ps[t] + ps[t + 128] + bq[col];
}

// K2: qp[b,h,d] = (1/8) * sum_j Wk[d, h*64+j] * q[b, h*64+j]
__global__ __launch_bounds__(256) void k_qp(const float* __restrict__ qin,
                                            const float* __restrict__ Wk,
                                            float* __restrict__ qp) {
    int b = blockIdx.x, dt = blockIdx.y;
    __shared__ float qs[DDIM];
    for (int i = threadIdx.x; i < DDIM; i += 256) qs[i] = qin[b * DDIM + i];
    __syncthreads();
    int h = threadIdx.x & 15, dl = threadIdx.x >> 4;
    int d = dt * 16 + dl;
    const float* wr = Wk + (size_t)d * DDIM + h * HDIM;
    const float* qh = qs + h * HDIM;
    float acc = 0.f;
#pragma unroll
    for (int j = 0; j < HDIM; ++j) acc = fmaf(wr[j], qh[j], acc);
    qp[((size_t)(b * NH + h)) * DDIM + d] = acc * SCALE;
}

// K2b: sb[b,h] = (1/8) * sum_j bk[h*64+j] * q[b, h*64+j]
__global__ __launch_bounds__(512) void k_sb(const float* __restrict__ qin,
                                            const float* __restrict__ bk,
                                            float* __restrict__ sb) {
    int idx = threadIdx.x;
    int b = idx >> 4, h = idx & 15;
    float acc = 0.f;
#pragma unroll
    for (int j = 0; j < HDIM; ++j)
        acc = fmaf(bk[h * HDIM + j], qin[b * DDIM + h * HDIM + j], acc);
    sb[idx] = acc * SCALE;
}

// K3: raw scores (no dist/mask — deferred to softmax); 2 rows per iter for ILP
__global__ __launch_bounds__(256) void k_scores(const float* __restrict__ ctx,
                                                const float* __restrict__ qp,
                                                const float* __restrict__ sb,
                                                float* __restrict__ scores, int N) {
    int b = blockIdx.x, n0 = blockIdx.y * 64;
    int lane = threadIdx.x & 63, w = threadIdx.x >> 6;
    int h0 = w * 4;
    float4 qr[4][4];
#pragma unroll
    for (int hh = 0; hh < 4; ++hh) {
        const float4* p = reinterpret_cast<const float4*>(
            qp + ((size_t)(b * NH + h0 + hh)) * DDIM + lane * 16);
        qr[hh][0] = p[0]; qr[hh][1] = p[1]; qr[hh][2] = p[2]; qr[hh][3] = p[3];
    }
    float sbr[4];
#pragma unroll
    for (int hh = 0; hh < 4; ++hh) sbr[hh] = sb[b * NH + h0 + hh];

    for (int r = 0; r < 64; r += 2) {
        const float4* cA = reinterpret_cast<const float4*>(
            ctx + ((size_t)b * N + n0 + r) * DDIM + lane * 16);
        const float4* cB = reinterpret_cast<const float4*>(
            ctx + ((size_t)b * N + n0 + r + 1) * DDIM + lane * 16);
        float4 a0 = cA[0], a1 = cA[1], a2 = cA[2], a3 = cA[3];
        float4 b0 = cB[0], b1 = cB[1], b2 = cB[2], b3 = cB[3];
        float p[2][4];
#pragma unroll
        for (int hh = 0; hh < 4; ++hh) {
            p[0][hh] = dot4(a0, qr[hh][0]) + dot4(a1, qr[hh][1]) +
                       dot4(a2, qr[hh][2]) + dot4(a3, qr[hh][3]);
            p[1][hh] = dot4(b0, qr[hh][0]) + dot4(b1, qr[hh][1]) +
                       dot4(b2, qr[hh][2]) + dot4(b3, qr[hh][3]);
        }
#pragma unroll
        for (int off = 32; off > 0; off >>= 1) {
#pragma unroll
            for (int rr = 0; rr < 2; ++rr)
#pragma unroll
                for (int hh = 0; hh < 4; ++hh)
                    p[rr][hh] += __shfl_xor(p[rr][hh], off, 64);
        }
        if (lane == 0) {
#pragma unroll
            for (int rr = 0; rr < 2; ++rr)
#pragma unroll
                for (int hh = 0; hh < 4; ++hh)
                    scores[((size_t)(b * NH + h0 + hh)) * N + n0 + r + rr] =
                        p[rr][hh] + sbr[hh];
        }
    }
}

// K4: softmax with dist-bias + mask applied here (coalesced [B,N] reads)
__global__ __launch_bounds__(256) void k_softmax(float* __restrict__ scores,
                                                 const float* __restrict__ dist,
                                                 const int* __restrict__ mask, int N) {
    int row = blockIdx.x;
    int b = row >> 4;
    float* s = scores + (size_t)row * N;
    int t = threadIdx.x;
    __shared__ float red[4];
    float v[16];
    float mx = -3.4e38f;
#pragma unroll
    for (int i = 0; i < 16; ++i) {
        int n = t + i * 256;
        float x = s[n] + dist[(size_t)b * N + n] * DLAM;
        if (mask[(size_t)b * N + n] == 0) x = -1e9f;
        v[i] = x;
        mx = fmaxf(mx, x);
    }
#pragma unroll
    for (int off = 32; off > 0; off >>= 1) mx = fmaxf(mx, __shfl_xor(mx, off, 64));
    if ((t & 63) == 0) red[t >> 6] = mx;
    __syncthreads();
    mx = fmaxf(fmaxf(red[0], red[1]), fmaxf(red[2], red[3]));
    __syncthreads();
    float sum = 0.f;
#pragma unroll
    for (int i = 0; i < 16; ++i) {
        v[i] = __expf(v[i] - mx);
        sum += v[i];
    }
#pragma unroll
    for (int off = 32; off > 0; off >>= 1) sum += __shfl_xor(sum, off, 64);
    if ((t & 63) == 0) red[t >> 6] = sum;
    __syncthreads();
    sum = red[0] + red[1] + red[2] + red[3];
    float inv = 1.f / sum;
#pragma unroll
    for (int i = 0; i < 16; ++i) s[t + i * 256] = v[i] * inv;
}

// K5: partial weighted ctx sum. Block = full D (256 thr x float4), all 16 heads/thread.
// part[(b*NS+ns)*NH+h][d] = sum_{n in chunk} attn[b,h,n] * ctx[b,n,d]
__global__ __launch_bounds__(256) void k_wsum(const float* __restrict__ ctx,
                                              const float* __restrict__ attn,
                                              float* __restrict__ part, int N) {
    int b = blockIdx.x, ns = blockIdx.y;
    int nchunk = N / NS;  // 128
    int nbase = ns * nchunk;
    __shared__ float smf[128][NH];
    for (int i = threadIdx.x; i < NH * 128; i += 256) {
        int h = i >> 7, nl = i & 127;
        smf[nl][h] = attn[((size_t)(b * NH + h)) * N + nbase + nl];
    }
    __syncthreads();
    int d4 = threadIdx.x * 4;
    float4 acc[16];
#pragma unroll
    for (int h = 0; h < 16; ++h) acc[h] = make_float4(0.f, 0.f, 0.f, 0.f);
    const float4* cp = reinterpret_cast<const float4*>(
        ctx + ((size_t)b * N + nbase) * DDIM + d4);
#pragma unroll 4
    for (int nl = 0; nl < 128; ++nl) {
        float4 cv = *cp;
        cp += DDIM / 4;
        float4 aa[4];
#pragma unroll
        for (int g = 0; g < 4; ++g)
            aa[g] = *reinterpret_cast<const float4*>(&smf[nl][g * 4]);
#pragma unroll
        for (int g = 0; g < 4; ++g) {
            float av[4] = {aa[g].x, aa[g].y, aa[g].z, aa[g].w};
#pragma unroll
            for (int j = 0; j < 4; ++j) {
                float a = av[j];
                int h = g * 4 + j;
                acc[h].x = fmaf(a, cv.x, acc[h].x);
                acc[h].y = fmaf(a, cv.y, acc[h].y);
                acc[h].z = fmaf(a, cv.z, acc[h].z);
                acc[h].w = fmaf(a, cv.w, acc[h].w);
            }
        }
    }
#pragma unroll
    for (int h = 0; h < 16; ++h) {
        float4* pp = reinterpret_cast<float4*>(
            part + (((size_t)(b * NS + ns)) * NH + h) * DDIM + d4);
        *pp = acc[h];
    }
}

// K6: reduce NS partials -> ctxa[b*NH+h][d]
__global__ __launch_bounds__(256) void k_red(const float* __restrict__ part,
                                             float* __restrict__ ctxa) {
    int row = blockIdx.x;  // b*16+h
    int b = row >> 4, h = row & 15;
    int t = threadIdx.x;
#pragma unroll
    for (int k = 0; k < 4; ++k) {
        int d = t + k * 256;
        float s = 0.f;
        for (int ns = 0; ns < NS; ++ns)
            s += part[(((size_t)(b * NS + ns)) * NH + h) * DDIM + d];
        ctxa[(size_t)row * DDIM + d] = s;
    }
}

// K7: oattn[b,c] = ctxa[b, c>>6, :] . Wv[:, c] + bv[c]; grid (B, 8)
__global__ __launch_bounds__(256) void k_vproj(const float* __restrict__ ctxa,
                                               const float* __restrict__ Wv,
                                               const float* __restrict__ bv,
                                               float* __restrict__ oattn) {
    int b = blockIdx.x, c0 = blockIdx.y * 128;
    int h0 = c0 >> 6;  // two heads: h0, h0+1
    __shared__ float cs[2][DDIM];
    __shared__ float ps[256];
    for (int i = threadIdx.x; i < 2 * DDIM; i += 256)
        cs[i >> 10][i & 1023] =
            ctxa[((size_t)(b * NH + h0 + (i >> 10))) * DDIM + (i & 1023)];
    __syncthreads();
    int t = threadIdx.x;
    int cl = t & 127;
    int col = c0 + cl;
    int hl = cl >> 6;
    int d0 = (t >> 7) * 512;
    float acc = 0.f;
    for (int d = d0; d < d0 + 512; ++d)
        acc = fmaf(cs[hl][d], Wv[(size_t)d * DDIM + col], acc);
    ps[t] = acc;
    __syncthreads();
    if (t < 128) oattn[b * DDIM + col] = ps[t] + ps[t + 128] + bv[col];
}

// K8: x[b,c] = query[b,c] + oattn[b,:] . Wo[:,c] + bo[c]; grid (B, 8)
__global__ __launch_bounds__(256) void k_oproj(const float* __restrict__ query,
                                               const float* __restrict__ oattn,
                                               const float* __restrict__ Wo,
                                               const float* __restrict__ bo,
                                               float* __restrict__ x) {
    int b = blockIdx.x, c0 = blockIdx.y * 128;
    __shared__ float os[DDIM];
    __shared__ float ps[256];
    for (int i = threadIdx.x; i < DDIM; i += 256) os[i] = oattn[b * DDIM + i];
    __syncthreads();
    int t = threadIdx.x;
    int col = c0 + (t & 127);
    int d0 = (t >> 7) * 512;
    float acc = 0.f;
    for (int d = d0; d < d0 + 512; ++d)
        acc = fmaf(os[d], Wo[(size_t)d * DDIM + col], acc);
    ps[t] = acc;
    __syncthreads();
    if (t < 128)
        x[b * DDIM + col] = query[b * DDIM + col] + ps[t] + ps[t + 128] + bo[col];
}

// K9: out = LayerNorm(x) * gamma + beta; grid B
__global__ __launch_bounds__(256) void k_ln(const float* __restrict__ x,
                                            const float* __restrict__ gamma,
                                            const float* __restrict__ beta,
                                            float* __restrict__ out) {
    int b = blockIdx.x;
    int t = threadIdx.x;
    __shared__ float red[8];
    float xv[4];
    float lsum = 0.f;
#pragma unroll
    for (int k = 0; k < 4; ++k) {
        xv[k] = x[b * DDIM + t + k * 256];
        lsum += xv[k];
    }
#pragma unroll
    for (int off = 32; off > 0; off >>= 1) lsum += __shfl_xor(lsum, off, 64);
    if ((t & 63) == 0) red[t >> 6] = lsum;
    __syncthreads();
    float mu = (red[0] + red[1] + red[2] + red[3]) * (1.f / DDIM);
    float lsq = 0.f;
#pragma unroll
    for (int k = 0; k < 4; ++k) {
        float dx = xv[k] - mu;
        lsq += dx * dx;
    }
#pragma unroll
    for (int off = 32; off > 0; off >>= 1) lsq += __shfl_xor(lsq, off, 64);
    if ((t & 63) == 0) red[4 + (t >> 6)] = lsq;
    __syncthreads();
    float var = (red[4] + red[5] + red[6] + red[7]) * (1.f / DDIM);
    float rstd = rsqrtf(var + LNEPS);
#pragma unroll
    for (int k = 0; k < 4; ++k) {
        int c = t + k * 256;
        out[b * DDIM + c] = (xv[k] - mu) * rstd * gamma[c] + beta[c];
    }
}

extern "C" void kernel_launch(void* const* d_in, const int* in_sizes, int n_in,
                              void* d_out, int out_size, void* d_ws, size_t ws_size,
                              hipStream_t stream) {
    const float* query = (const float*)d_in[0];
    const float* ctx   = (const float*)d_in[1];
    const float* dist  = (const float*)d_in[2];
    const int*   mask  = (const int*)d_in[3];
    const float* Wq = (const float*)d_in[4];
    const float* bq = (const float*)d_in[5];
    const float* Wk = (const float*)d_in[6];
    const float* bk = (const float*)d_in[7];
    const float* Wv = (const float*)d_in[8];
    const float* bv = (const float*)d_in[9];
    const float* Wo = (const float*)d_in[10];
    const float* bo = (const float*)d_in[11];
    const float* gamma = (const float*)d_in[12];
    const float* beta  = (const float*)d_in[13];
    float* out = (float*)d_out;

    int B = in_sizes[0] / DDIM;        // 32
    int N = in_sizes[1] / (B * DDIM);  // 4096

    float* ws = (float*)d_ws;
    float* q      = ws;                                   // B*D
    float* qp     = q + (size_t)B * DDIM;                 // B*H*D
    float* sb     = qp + (size_t)B * NH * DDIM;           // B*H
    float* scores = sb + (size_t)B * NH;                  // B*H*N
    float* part   = scores + (size_t)B * NH * N;          // B*NS*H*D
    float* ctxa   = part + (size_t)B * NS * NH * DDIM;    // B*H*D
    float* oattn  = ctxa + (size_t)B * NH * DDIM;         // B*D
    float* xbuf   = oattn + (size_t)B * DDIM;             // B*D

    k_q<<<dim3(B, 8), 256, 0, stream>>>(query, Wq, bq, q);
    k_qp<<<dim3(B, DDIM / 16), 256, 0, stream>>>(q, Wk, qp);
    k_sb<<<1, B * NH, 0, stream>>>(q, bk, sb);
    k_scores<<<dim3(B, N / 64), 256, 0, stream>>>(ctx, qp, sb, scores, N);
    k_softmax<<<B * NH, 256, 0, stream>>>(scores, dist, mask, N);
    k_wsum<<<dim3(B, NS), 256, 0, stream>>>(ctx, scores, part, N);
    k_red<<<B * NH, 256, 0, stream>>>(part, ctxa);
    k_vproj<<<dim3(B, 8), 256, 0, stream>>>(ctxa, Wv, bv, oattn);
    k_oproj<<<dim3(B, 8), 256, 0, stream>>>(query, oattn, Wo, bo, xbuf);
    k_ln<<<B, 256, 0, stream>>>(xbuf, gamma, beta, out);
}

// Round 3
// 875.970 us; speedup vs baseline: 1.1538x; 1.1538x over previous
//
#include <hip/hip_runtime.h>
#include <math.h>

#define DDIM 1024
#define NH 16
#define HDIM 64
#define SCALE 0.125f
#define DLAM -0.1f
#define LNEPS 1e-5f
#define NS 16
#define RPB 256  // rows (n) per flash block

__device__ inline float dot4(float4 a, float4 b) {
    return fmaf(a.x, b.x, fmaf(a.y, b.y, fmaf(a.z, b.z, a.w * b.w)));
}

// K1: q[b,c] = query[b,:] @ Wq[:,c] + bq[c]; grid (B, 8)
__global__ __launch_bounds__(256) void k_q(const float* __restrict__ query,
                                           const float* __restrict__ Wq,
                                           const float* __restrict__ bq,
                                           float* __restrict__ qout) {
    int b = blockIdx.x, c0 = blockIdx.y * 128;
    __shared__ float qs[DDIM];
    __shared__ float ps[256];
    for (int i = threadIdx.x; i < DDIM; i += 256) qs[i] = query[b * DDIM + i];
    __syncthreads();
    int t = threadIdx.x;
    int col = c0 + (t & 127);
    int d0 = (t >> 7) * 512;
    float acc = 0.f;
    for (int d = d0; d < d0 + 512; ++d) acc = fmaf(qs[d], Wq[(size_t)d * DDIM + col], acc);
    ps[t] = acc;
    __syncthreads();
    if (t < 128) qout[b * DDIM + col] = ps[t] + ps[t + 128] + bq[col];
}

// K2: qp[b,h,d] = SCALE * sum_j Wk[d, h*64+j] * q[b, h*64+j]
__global__ __launch_bounds__(256) void k_qp(const float* __restrict__ qin,
                                            const float* __restrict__ Wk,
                                            float* __restrict__ qp) {
    int b = blockIdx.x, dt = blockIdx.y;
    __shared__ float qs[DDIM];
    for (int i = threadIdx.x; i < DDIM; i += 256) qs[i] = qin[b * DDIM + i];
    __syncthreads();
    int h = threadIdx.x & 15, dl = threadIdx.x >> 4;
    int d = dt * 16 + dl;
    const float* wr = Wk + (size_t)d * DDIM + h * HDIM;
    const float* qh = qs + h * HDIM;
    float acc = 0.f;
#pragma unroll
    for (int j = 0; j < HDIM; ++j) acc = fmaf(wr[j], qh[j], acc);
    qp[((size_t)(b * NH + h)) * DDIM + d] = acc * SCALE;
}

// K2b: sb[b,h] = SCALE * sum_j bk[h*64+j] * q[b, h*64+j]
__global__ __launch_bounds__(512) void k_sb(const float* __restrict__ qin,
                                            const float* __restrict__ bk,
                                            float* __restrict__ sb) {
    int idx = threadIdx.x;
    int b = idx >> 4, h = idx & 15;
    float acc = 0.f;
#pragma unroll
    for (int j = 0; j < HDIM; ++j)
        acc = fmaf(bk[h * HDIM + j], qin[b * DDIM + h * HDIM + j], acc);
    sb[idx] = acc * SCALE;
}

// K3: fused flash pass. ctx read ONCE. Per block: 256 rows, 4 waves x 4 heads.
// Online softmax entirely in registers; unnormalized A/m/l written per chunk.
__global__ __launch_bounds__(256) void k_flash(const float* __restrict__ ctx,
                                               const float* __restrict__ qp,
                                               const float* __restrict__ sb,
                                               const float* __restrict__ dist,
                                               const int* __restrict__ mask,
                                               float* __restrict__ partA,
                                               float* __restrict__ partM,
                                               float* __restrict__ partL, int N) {
    int b = blockIdx.x, ns = blockIdx.y;
    int nbase = ns * RPB;
    __shared__ float dls[RPB];
    __shared__ int mks[RPB];
    int t = threadIdx.x;
    dls[t] = dist[(size_t)b * N + nbase + t] * DLAM;
    mks[t] = mask[(size_t)b * N + nbase + t];
    __syncthreads();

    int lane = t & 63, w = t >> 6, h0 = w * 4;
    float4 qr[4][4];
    float sbr[4];
#pragma unroll
    for (int hh = 0; hh < 4; ++hh) {
        const float4* p = reinterpret_cast<const float4*>(
            qp + ((size_t)(b * NH + h0 + hh)) * DDIM + lane * 16);
        qr[hh][0] = p[0]; qr[hh][1] = p[1]; qr[hh][2] = p[2]; qr[hh][3] = p[3];
        sbr[hh] = sb[b * NH + h0 + hh];
    }

    float m[4], l[4];
    float4 acc[4][4];
#pragma unroll
    for (int hh = 0; hh < 4; ++hh) {
        m[hh] = -1e30f;
        l[hh] = 0.f;
#pragma unroll
        for (int k = 0; k < 4; ++k) acc[hh][k] = make_float4(0.f, 0.f, 0.f, 0.f);
    }

    const float* rowp = ctx + ((size_t)b * N + nbase) * DDIM + lane * 16;
    for (int r = 0; r < RPB; r += 2) {
        const float4* cA = reinterpret_cast<const float4*>(rowp);
        const float4* cB = reinterpret_cast<const float4*>(rowp + DDIM);
        float4 a0 = cA[0], a1 = cA[1], a2 = cA[2], a3 = cA[3];
        float4 b0 = cB[0], b1 = cB[1], b2 = cB[2], b3 = cB[3];
        float p[2][4];
#pragma unroll
        for (int hh = 0; hh < 4; ++hh) {
            p[0][hh] = dot4(a0, qr[hh][0]) + dot4(a1, qr[hh][1]) +
                       dot4(a2, qr[hh][2]) + dot4(a3, qr[hh][3]);
            p[1][hh] = dot4(b0, qr[hh][0]) + dot4(b1, qr[hh][1]) +
                       dot4(b2, qr[hh][2]) + dot4(b3, qr[hh][3]);
        }
#pragma unroll
        for (int off = 32; off > 0; off >>= 1) {
#pragma unroll
            for (int rr = 0; rr < 2; ++rr)
#pragma unroll
                for (int hh = 0; hh < 4; ++hh)
                    p[rr][hh] += __shfl_xor(p[rr][hh], off, 64);
        }
        // rr = 0 (row r): all lanes hold identical p -> uniform branches
        {
            float dv = dls[r];
            int mk = mks[r];
#pragma unroll
            for (int hh = 0; hh < 4; ++hh) {
                float s = mk ? (p[0][hh] + sbr[hh] + dv) : -1e9f;
                if (__any(s - m[hh] > 8.f)) {
                    float f = __expf(m[hh] - s);
                    l[hh] *= f;
#pragma unroll
                    for (int k = 0; k < 4; ++k) {
                        acc[hh][k].x *= f; acc[hh][k].y *= f;
                        acc[hh][k].z *= f; acc[hh][k].w *= f;
                    }
                    m[hh] = s;
                }
                float e = __expf(s - m[hh]);
                l[hh] += e;
                acc[hh][0].x = fmaf(e, a0.x, acc[hh][0].x);
                acc[hh][0].y = fmaf(e, a0.y, acc[hh][0].y);
                acc[hh][0].z = fmaf(e, a0.z, acc[hh][0].z);
                acc[hh][0].w = fmaf(e, a0.w, acc[hh][0].w);
                acc[hh][1].x = fmaf(e, a1.x, acc[hh][1].x);
                acc[hh][1].y = fmaf(e, a1.y, acc[hh][1].y);
                acc[hh][1].z = fmaf(e, a1.z, acc[hh][1].z);
                acc[hh][1].w = fmaf(e, a1.w, acc[hh][1].w);
                acc[hh][2].x = fmaf(e, a2.x, acc[hh][2].x);
                acc[hh][2].y = fmaf(e, a2.y, acc[hh][2].y);
                acc[hh][2].z = fmaf(e, a2.z, acc[hh][2].z);
                acc[hh][2].w = fmaf(e, a2.w, acc[hh][2].w);
                acc[hh][3].x = fmaf(e, a3.x, acc[hh][3].x);
                acc[hh][3].y = fmaf(e, a3.y, acc[hh][3].y);
                acc[hh][3].z = fmaf(e, a3.z, acc[hh][3].z);
                acc[hh][3].w = fmaf(e, a3.w, acc[hh][3].w);
            }
        }
        // rr = 1 (row r+1)
        {
            float dv = dls[r + 1];
            int mk = mks[r + 1];
#pragma unroll
            for (int hh = 0; hh < 4; ++hh) {
                float s = mk ? (p[1][hh] + sbr[hh] + dv) : -1e9f;
                if (__any(s - m[hh] > 8.f)) {
                    float f = __expf(m[hh] - s);
                    l[hh] *= f;
#pragma unroll
                    for (int k = 0; k < 4; ++k) {
                        acc[hh][k].x *= f; acc[hh][k].y *= f;
                        acc[hh][k].z *= f; acc[hh][k].w *= f;
                    }
                    m[hh] = s;
                }
                float e = __expf(s - m[hh]);
                l[hh] += e;
                acc[hh][0].x = fmaf(e, b0.x, acc[hh][0].x);
                acc[hh][0].y = fmaf(e, b0.y, acc[hh][0].y);
                acc[hh][0].z = fmaf(e, b0.z, acc[hh][0].z);
                acc[hh][0].w = fmaf(e, b0.w, acc[hh][0].w);
                acc[hh][1].x = fmaf(e, b1.x, acc[hh][1].x);
                acc[hh][1].y = fmaf(e, b1.y, acc[hh][1].y);
                acc[hh][1].z = fmaf(e, b1.z, acc[hh][1].z);
                acc[hh][1].w = fmaf(e, b1.w, acc[hh][1].w);
                acc[hh][2].x = fmaf(e, b2.x, acc[hh][2].x);
                acc[hh][2].y = fmaf(e, b2.y, acc[hh][2].y);
                acc[hh][2].z = fmaf(e, b2.z, acc[hh][2].z);
                acc[hh][2].w = fmaf(e, b2.w, acc[hh][2].w);
                acc[hh][3].x = fmaf(e, b3.x, acc[hh][3].x);
                acc[hh][3].y = fmaf(e, b3.y, acc[hh][3].y);
                acc[hh][3].z = fmaf(e, b3.z, acc[hh][3].z);
                acc[hh][3].w = fmaf(e, b3.w, acc[hh][3].w);
            }
        }
        rowp += 2 * DDIM;
    }

    // write unnormalized A (coalesced: 64 lanes x 16B contiguous per head)
#pragma unroll
    for (int hh = 0; hh < 4; ++hh) {
        float* dst = partA + (((size_t)((b * NS + ns) * NH + h0 + hh))) * DDIM + lane * 16;
#pragma unroll
        for (int k = 0; k < 4; ++k)
            *reinterpret_cast<float4*>(dst + k * 4) = acc[hh][k];
    }
    if (lane == 0) {
#pragma unroll
        for (int hh = 0; hh < 4; ++hh) {
            int idx = (b * NS + ns) * NH + h0 + hh;
            partM[idx] = m[hh];
            partL[idx] = l[hh];
        }
    }
}

// K4: merge chunk partials: ctxa[b,h,d] = sum_ns W_ns*A_ns[d] / sum_ns W_ns*l_ns
__global__ __launch_bounds__(256) void k_comb(const float* __restrict__ partA,
                                              const float* __restrict__ partM,
                                              const float* __restrict__ partL,
                                              float* __restrict__ ctxa) {
    int row = blockIdx.x;  // b*NH + h
    int b = row >> 4, h = row & 15;
    float M = -1e30f;
#pragma unroll
    for (int ns = 0; ns < NS; ++ns)
        M = fmaxf(M, partM[(b * NS + ns) * NH + h]);
    float Wn[NS];
    float denom = 0.f;
#pragma unroll
    for (int ns = 0; ns < NS; ++ns) {
        Wn[ns] = __expf(partM[(b * NS + ns) * NH + h] - M);
        denom = fmaf(Wn[ns], partL[(b * NS + ns) * NH + h], denom);
    }
    float inv = 1.f / denom;
    int d4 = threadIdx.x * 4;
    float4 a = make_float4(0.f, 0.f, 0.f, 0.f);
#pragma unroll
    for (int ns = 0; ns < NS; ++ns) {
        float4 v = *reinterpret_cast<const float4*>(
            partA + (((size_t)((b * NS + ns) * NH + h))) * DDIM + d4);
        float wv = Wn[ns];
        a.x = fmaf(wv, v.x, a.x);
        a.y = fmaf(wv, v.y, a.y);
        a.z = fmaf(wv, v.z, a.z);
        a.w = fmaf(wv, v.w, a.w);
    }
    float4 o = make_float4(a.x * inv, a.y * inv, a.z * inv, a.w * inv);
    *reinterpret_cast<float4*>(ctxa + (size_t)row * DDIM + d4) = o;
}

// K5: oattn[b,c] = ctxa[b, c>>6, :] . Wv[:, c] + bv[c]; grid (B, 8)
__global__ __launch_bounds__(256) void k_vproj(const float* __restrict__ ctxa,
                                               const float* __restrict__ Wv,
                                               const float* __restrict__ bv,
                                               float* __restrict__ oattn) {
    int b = blockIdx.x, c0 = blockIdx.y * 128;
    int h0 = c0 >> 6;
    __shared__ float cs[2][DDIM];
    __shared__ float ps[256];
    for (int i = threadIdx.x; i < 2 * DDIM; i += 256)
        cs[i >> 10][i & 1023] =
            ctxa[((size_t)(b * NH + h0 + (i >> 10))) * DDIM + (i & 1023)];
    __syncthreads();
    int t = threadIdx.x;
    int cl = t & 127;
    int col = c0 + cl;
    int hl = cl >> 6;
    int d0 = (t >> 7) * 512;
    float acc = 0.f;
    for (int d = d0; d < d0 + 512; ++d)
        acc = fmaf(cs[hl][d], Wv[(size_t)d * DDIM + col], acc);
    ps[t] = acc;
    __syncthreads();
    if (t < 128) oattn[b * DDIM + col] = ps[t] + ps[t + 128] + bv[col];
}

// K6: x[b,c] = query[b,c] + oattn[b,:] . Wo[:,c] + bo[c]; grid (B, 8)
__global__ __launch_bounds__(256) void k_oproj(const float* __restrict__ query,
                                               const float* __restrict__ oattn,
                                               const float* __restrict__ Wo,
                                               const float* __restrict__ bo,
                                               float* __restrict__ x) {
    int b = blockIdx.x, c0 = blockIdx.y * 128;
    __shared__ float os[DDIM];
    __shared__ float ps[256];
    for (int i = threadIdx.x; i < DDIM; i += 256) os[i] = oattn[b * DDIM + i];
    __syncthreads();
    int t = threadIdx.x;
    int col = c0 + (t & 127);
    int d0 = (t >> 7) * 512;
    float acc = 0.f;
    for (int d = d0; d < d0 + 512; ++d)
        acc = fmaf(os[d], Wo[(size_t)d * DDIM + col], acc);
    ps[t] = acc;
    __syncthreads();
    if (t < 128)
        x[b * DDIM + col] = query[b * DDIM + col] + ps[t] + ps[t + 128] + bo[col];
}

// K7: out = LayerNorm(x) * gamma + beta; grid B
__global__ __launch_bounds__(256) void k_ln(const float* __restrict__ x,
                                            const float* __restrict__ gamma,
                                            const float* __restrict__ beta,
                                            float* __restrict__ out) {
    int b = blockIdx.x;
    int t = threadIdx.x;
    __shared__ float red[8];
    float xv[4];
    float lsum = 0.f;
#pragma unroll
    for (int k = 0; k < 4; ++k) {
        xv[k] = x[b * DDIM + t + k * 256];
        lsum += xv[k];
    }
#pragma unroll
    for (int off = 32; off > 0; off >>= 1) lsum += __shfl_xor(lsum, off, 64);
    if ((t & 63) == 0) red[t >> 6] = lsum;
    __syncthreads();
    float mu = (red[0] + red[1] + red[2] + red[3]) * (1.f / DDIM);
    float lsq = 0.f;
#pragma unroll
    for (int k = 0; k < 4; ++k) {
        float dx = xv[k] - mu;
        lsq += dx * dx;
    }
#pragma unroll
    for (int off = 32; off > 0; off >>= 1) lsq += __shfl_xor(lsq, off, 64);
    if ((t & 63) == 0) red[4 + (t >> 6)] = lsq;
    __syncthreads();
    float var = (red[4] + red[5] + red[6] + red[7]) * (1.f / DDIM);
    float rstd = rsqrtf(var + LNEPS);
#pragma unroll
    for (int k = 0; k < 4; ++k) {
        int c = t + k * 256;
        out[b * DDIM + c] = (xv[k] - mu) * rstd * gamma[c] + beta[c];
    }
}

extern "C" void kernel_launch(void* const* d_in, const int* in_sizes, int n_in,
                              void* d_out, int out_size, void* d_ws, size_t ws_size,
                              hipStream_t stream) {
    const float* query = (const float*)d_in[0];
    const float* ctx   = (const float*)d_in[1];
    const float* dist  = (const float*)d_in[2];
    const int*   mask  = (const int*)d_in[3];
    const float* Wq = (const float*)d_in[4];
    const float* bq = (const float*)d_in[5];
    const float* Wk = (const float*)d_in[6];
    const float* bk = (const float*)d_in[7];
    const float* Wv = (const float*)d_in[8];
    const float* bv = (const float*)d_in[9];
    const float* Wo = (const float*)d_in[10];
    const float* bo = (const float*)d_in[11];
    const float* gamma = (const float*)d_in[12];
    const float* beta  = (const float*)d_in[13];
    float* out = (float*)d_out;

    int B = in_sizes[0] / DDIM;        // 32
    int N = in_sizes[1] / (B * DDIM);  // 4096

    float* ws = (float*)d_ws;
    float* q      = ws;                                   // B*D
    float* qp     = q + (size_t)B * DDIM;                 // B*H*D
    float* sb     = qp + (size_t)B * NH * DDIM;           // B*H
    float* partA  = sb + (size_t)B * NH;                  // B*NS*H*D
    float* partM  = partA + (size_t)B * NS * NH * DDIM;   // B*NS*H
    float* partL  = partM + (size_t)B * NS * NH;          // B*NS*H
    float* ctxa   = partL + (size_t)B * NS * NH;          // B*H*D
    float* oattn  = ctxa + (size_t)B * NH * DDIM;         // B*D
    float* xbuf   = oattn + (size_t)B * DDIM;             // B*D

    k_q<<<dim3(B, 8), 256, 0, stream>>>(query, Wq, bq, q);
    k_qp<<<dim3(B, DDIM / 16), 256, 0, stream>>>(q, Wk, qp);
    k_sb<<<1, B * NH, 0, stream>>>(q, bk, sb);
    k_flash<<<dim3(B, NS), 256, 0, stream>>>(ctx, qp, sb, dist, mask,
                                             partA, partM, partL, N);
    k_comb<<<B * NH, 256, 0, stream>>>(partA, partM, partL, ctxa);
    k_vproj<<<dim3(B, 8), 256, 0, stream>>>(ctxa, Wv, bv, oattn);
    k_oproj<<<dim3(B, 8), 256, 0, stream>>>(query, oattn, Wo, bo, xbuf);
    k_ln<<<B, 256, 0, stream>>>(xbuf, gamma, beta, out);
}

// Round 4
// 479.996 us; speedup vs baseline: 2.1056x; 1.8250x over previous
//
#include <hip/hip_runtime.h>
#include <math.h>

#define DDIM 1024
#define NH 16
#define HDIM 64
#define SCALE 0.125f
#define DLAM -0.1f
#define LNEPS 1e-5f
#define NS 16
#define RPB 256  // rows (n) per flash block

__device__ inline float dot4(float4 a, float4 b) {
    return fmaf(a.x, b.x, fmaf(a.y, b.y, fmaf(a.z, b.z, a.w * b.w)));
}

// K1: q[b,c] = query[b,:] @ Wq[:,c] + bq[c]; grid (B,8), 512 thr, 4-way d-split
__global__ __launch_bounds__(512) void k_q(const float* __restrict__ query,
                                           const float* __restrict__ Wq,
                                           const float* __restrict__ bq,
                                           float* __restrict__ qout) {
    int b = blockIdx.x, c0 = blockIdx.y * 128;
    __shared__ float qs[DDIM];
    __shared__ float ps[512];
    int t = threadIdx.x;
    for (int i = t; i < DDIM; i += 512) qs[i] = query[b * DDIM + i];
    __syncthreads();
    int cl = t & 127;
    int col = c0 + cl;
    int d0 = (t >> 7) * 256;
    float acc = 0.f;
#pragma unroll 8
    for (int d = d0; d < d0 + 256; ++d)
        acc = fmaf(qs[d], Wq[(size_t)d * DDIM + col], acc);
    ps[t] = acc;
    __syncthreads();
    if (t < 128)
        qout[b * DDIM + col] = ps[t] + ps[t + 128] + ps[t + 256] + ps[t + 384] + bq[col];
}

// K2: qp[b,h,d] = SCALE * sum_j Wk[d, h*64+j] * q[b, h*64+j]
__global__ __launch_bounds__(256) void k_qp(const float* __restrict__ qin,
                                            const float* __restrict__ Wk,
                                            float* __restrict__ qp) {
    int b = blockIdx.x, dt = blockIdx.y;
    __shared__ float qs[DDIM];
    for (int i = threadIdx.x; i < DDIM; i += 256) qs[i] = qin[b * DDIM + i];
    __syncthreads();
    int h = threadIdx.x & 15, dl = threadIdx.x >> 4;
    int d = dt * 16 + dl;
    const float* wr = Wk + (size_t)d * DDIM + h * HDIM;
    const float* qh = qs + h * HDIM;
    float acc = 0.f;
#pragma unroll
    for (int j = 0; j < HDIM; ++j) acc = fmaf(wr[j], qh[j], acc);
    qp[((size_t)(b * NH + h)) * DDIM + d] = acc * SCALE;
}

// K2b: sb[b,h] = SCALE * sum_j bk[h*64+j] * q[b, h*64+j]
__global__ __launch_bounds__(512) void k_sb(const float* __restrict__ qin,
                                            const float* __restrict__ bk,
                                            float* __restrict__ sb) {
    int idx = threadIdx.x;
    int b = idx >> 4, h = idx & 15;
    float acc = 0.f;
#pragma unroll
    for (int j = 0; j < HDIM; ++j)
        acc = fmaf(bk[h * HDIM + j], qin[b * DDIM + h * HDIM + j], acc);
    sb[idx] = acc * SCALE;
}

// K3: fused flash pass. 512 thr = 8 waves x 2 heads. ctx read once.
__global__ __launch_bounds__(512) void k_flash(const float* __restrict__ ctx,
                                               const float* __restrict__ qp,
                                               const float* __restrict__ sb,
                                               const float* __restrict__ dist,
                                               const int* __restrict__ mask,
                                               float* __restrict__ partA,
                                               float* __restrict__ partM,
                                               float* __restrict__ partL, int N) {
    int b = blockIdx.x, ns = blockIdx.y;
    int nbase = ns * RPB;
    __shared__ float dls[RPB];
    __shared__ int mks[RPB];
    int t = threadIdx.x;
    if (t < RPB) {
        dls[t] = dist[(size_t)b * N + nbase + t] * DLAM;
        mks[t] = mask[(size_t)b * N + nbase + t];
    }
    __syncthreads();

    int lane = t & 63, w = t >> 6;
    int h0 = w * 2;
    float4 qr[2][4];
    float sbr[2];
#pragma unroll
    for (int hh = 0; hh < 2; ++hh) {
        const float4* p = reinterpret_cast<const float4*>(
            qp + ((size_t)(b * NH + h0 + hh)) * DDIM + lane * 16);
        qr[hh][0] = p[0]; qr[hh][1] = p[1]; qr[hh][2] = p[2]; qr[hh][3] = p[3];
        sbr[hh] = sb[b * NH + h0 + hh];
    }

    float m[2] = {-1e30f, -1e30f}, l[2] = {0.f, 0.f};
    float4 acc[2][4];
#pragma unroll
    for (int hh = 0; hh < 2; ++hh)
#pragma unroll
        for (int k = 0; k < 4; ++k) acc[hh][k] = make_float4(0.f, 0.f, 0.f, 0.f);

    const float* rowp = ctx + ((size_t)b * N + nbase) * DDIM + lane * 16;
    for (int r = 0; r < RPB; ++r) {
        const float4* c = reinterpret_cast<const float4*>(rowp);
        float4 c0 = c[0], c1 = c[1], c2 = c[2], c3 = c[3];
        float p0 = dot4(c0, qr[0][0]) + dot4(c1, qr[0][1]) +
                   dot4(c2, qr[0][2]) + dot4(c3, qr[0][3]);
        float p1 = dot4(c0, qr[1][0]) + dot4(c1, qr[1][1]) +
                   dot4(c2, qr[1][2]) + dot4(c3, qr[1][3]);
#pragma unroll
        for (int off = 32; off > 0; off >>= 1) {
            p0 += __shfl_xor(p0, off, 64);
            p1 += __shfl_xor(p1, off, 64);
        }
        float dv = dls[r];
        int mk = mks[r];
        float pv[2] = {p0, p1};
#pragma unroll
        for (int hh = 0; hh < 2; ++hh) {
            float s = mk ? (pv[hh] + sbr[hh] + dv) : -1e9f;
            if (__any(s - m[hh] > 8.f)) {
                float f = __expf(m[hh] - s);
                l[hh] *= f;
#pragma unroll
                for (int k = 0; k < 4; ++k) {
                    acc[hh][k].x *= f; acc[hh][k].y *= f;
                    acc[hh][k].z *= f; acc[hh][k].w *= f;
                }
                m[hh] = s;
            }
            float e = __expf(s - m[hh]);
            l[hh] += e;
            acc[hh][0].x = fmaf(e, c0.x, acc[hh][0].x);
            acc[hh][0].y = fmaf(e, c0.y, acc[hh][0].y);
            acc[hh][0].z = fmaf(e, c0.z, acc[hh][0].z);
            acc[hh][0].w = fmaf(e, c0.w, acc[hh][0].w);
            acc[hh][1].x = fmaf(e, c1.x, acc[hh][1].x);
            acc[hh][1].y = fmaf(e, c1.y, acc[hh][1].y);
            acc[hh][1].z = fmaf(e, c1.z, acc[hh][1].z);
            acc[hh][1].w = fmaf(e, c1.w, acc[hh][1].w);
            acc[hh][2].x = fmaf(e, c2.x, acc[hh][2].x);
            acc[hh][2].y = fmaf(e, c2.y, acc[hh][2].y);
            acc[hh][2].z = fmaf(e, c2.z, acc[hh][2].z);
            acc[hh][2].w = fmaf(e, c2.w, acc[hh][2].w);
            acc[hh][3].x = fmaf(e, c3.x, acc[hh][3].x);
            acc[hh][3].y = fmaf(e, c3.y, acc[hh][3].y);
            acc[hh][3].z = fmaf(e, c3.z, acc[hh][3].z);
            acc[hh][3].w = fmaf(e, c3.w, acc[hh][3].w);
        }
        rowp += DDIM;
    }

#pragma unroll
    for (int hh = 0; hh < 2; ++hh) {
        float* dst = partA + ((size_t)((b * NS + ns) * NH + h0 + hh)) * DDIM + lane * 16;
#pragma unroll
        for (int k = 0; k < 4; ++k)
            *reinterpret_cast<float4*>(dst + k * 4) = acc[hh][k];
    }
    if (lane == 0) {
#pragma unroll
        for (int hh = 0; hh < 2; ++hh) {
            int idx = (b * NS + ns) * NH + h0 + hh;
            partM[idx] = m[hh];
            partL[idx] = l[hh];
        }
    }
}

// K4: merge chunk partials -> ctxa[b,h,d]
__global__ __launch_bounds__(256) void k_comb(const float* __restrict__ partA,
                                              const float* __restrict__ partM,
                                              const float* __restrict__ partL,
                                              float* __restrict__ ctxa) {
    int row = blockIdx.x;  // b*NH + h
    int b = row >> 4, h = row & 15;
    float M = -1e30f;
#pragma unroll
    for (int ns = 0; ns < NS; ++ns)
        M = fmaxf(M, partM[(b * NS + ns) * NH + h]);
    float Wn[NS];
    float denom = 0.f;
#pragma unroll
    for (int ns = 0; ns < NS; ++ns) {
        Wn[ns] = __expf(partM[(b * NS + ns) * NH + h] - M);
        denom = fmaf(Wn[ns], partL[(b * NS + ns) * NH + h], denom);
    }
    float inv = 1.f / denom;
    int d4 = threadIdx.x * 4;
    float4 a = make_float4(0.f, 0.f, 0.f, 0.f);
#pragma unroll
    for (int ns = 0; ns < NS; ++ns) {
        float4 v = *reinterpret_cast<const float4*>(
            partA + ((size_t)((b * NS + ns) * NH + h)) * DDIM + d4);
        float wv = Wn[ns];
        a.x = fmaf(wv, v.x, a.x);
        a.y = fmaf(wv, v.y, a.y);
        a.z = fmaf(wv, v.z, a.z);
        a.w = fmaf(wv, v.w, a.w);
    }
    float4 o = make_float4(a.x * inv, a.y * inv, a.z * inv, a.w * inv);
    *reinterpret_cast<float4*>(ctxa + (size_t)row * DDIM + d4) = o;
}

// K5: fused epilogue: oattn = ctxa.Wv+bv ; x = query + oattn.Wo+bo ; out = LN(x)
__global__ __launch_bounds__(512) void k_epi(const float* __restrict__ ctxa,
                                             const float* __restrict__ Wv,
                                             const float* __restrict__ bv,
                                             const float* __restrict__ Wo,
                                             const float* __restrict__ bo,
                                             const float* __restrict__ query,
                                             const float* __restrict__ gamma,
                                             const float* __restrict__ beta,
                                             float* __restrict__ out) {
    int b = blockIdx.x, t = threadIdx.x;
    __shared__ float cs[NH * DDIM];   // 64 KB
    __shared__ float vec[DDIM];
    __shared__ float xs[DDIM];
    __shared__ float ps[4][2][256];   // 8 KB
    __shared__ float red[16];
    for (int i = t; i < NH * DDIM; i += 512)
        cs[i] = ctxa[(size_t)b * NH * DDIM + i];
    __syncthreads();

    int cl = t & 255, dh = t >> 8;
    // ---- vproj ----
    {
        int c0 = cl, c1 = cl + 256, c2 = cl + 512, c3 = cl + 768;
        const float* r0 = cs + (c0 >> 6) * DDIM;
        const float* r1 = cs + (c1 >> 6) * DDIM;
        const float* r2 = cs + (c2 >> 6) * DDIM;
        const float* r3 = cs + (c3 >> 6) * DDIM;
        float a0 = 0.f, a1 = 0.f, a2 = 0.f, a3 = 0.f;
#pragma unroll 4
        for (int d = dh * 512; d < dh * 512 + 512; ++d) {
            const float* wr = Wv + (size_t)d * DDIM;
            a0 = fmaf(r0[d], wr[c0], a0);
            a1 = fmaf(r1[d], wr[c1], a1);
            a2 = fmaf(r2[d], wr[c2], a2);
            a3 = fmaf(r3[d], wr[c3], a3);
        }
        ps[0][dh][cl] = a0; ps[1][dh][cl] = a1;
        ps[2][dh][cl] = a2; ps[3][dh][cl] = a3;
    }
    __syncthreads();
    if (t < 256) {
#pragma unroll
        for (int k = 0; k < 4; ++k)
            vec[t + k * 256] = ps[k][0][t] + ps[k][1][t] + bv[t + k * 256];
    }
    __syncthreads();
    // ---- oproj + residual ----
    {
        int c0 = cl, c1 = cl + 256, c2 = cl + 512, c3 = cl + 768;
        float a0 = 0.f, a1 = 0.f, a2 = 0.f, a3 = 0.f;
#pragma unroll 4
        for (int d = dh * 512; d < dh * 512 + 512; ++d) {
            float ov = vec[d];
            const float* wr = Wo + (size_t)d * DDIM;
            a0 = fmaf(ov, wr[c0], a0);
            a1 = fmaf(ov, wr[c1], a1);
            a2 = fmaf(ov, wr[c2], a2);
            a3 = fmaf(ov, wr[c3], a3);
        }
        ps[0][dh][cl] = a0; ps[1][dh][cl] = a1;
        ps[2][dh][cl] = a2; ps[3][dh][cl] = a3;
    }
    __syncthreads();
    if (t < 256) {
#pragma unroll
        for (int k = 0; k < 4; ++k) {
            int c = t + k * 256;
            xs[c] = query[b * DDIM + c] + ps[k][0][t] + ps[k][1][t] + bo[c];
        }
    }
    __syncthreads();
    // ---- LayerNorm (512 thr, 2 elems each) ----
    float x0 = xs[t], x1 = xs[t + 512];
    float lsum = x0 + x1;
#pragma unroll
    for (int off = 32; off > 0; off >>= 1) lsum += __shfl_xor(lsum, off, 64);
    if ((t & 63) == 0) red[t >> 6] = lsum;
    __syncthreads();
    float mu = 0.f;
#pragma unroll
    for (int w = 0; w < 8; ++w) mu += red[w];
    mu *= (1.f / DDIM);
    float d0 = x0 - mu, d1 = x1 - mu;
    float lsq = d0 * d0 + d1 * d1;
#pragma unroll
    for (int off = 32; off > 0; off >>= 1) lsq += __shfl_xor(lsq, off, 64);
    if ((t & 63) == 0) red[8 + (t >> 6)] = lsq;
    __syncthreads();
    float var = 0.f;
#pragma unroll
    for (int w = 0; w < 8; ++w) var += red[8 + w];
    var *= (1.f / DDIM);
    float rstd = rsqrtf(var + LNEPS);
    out[b * DDIM + t] = d0 * rstd * gamma[t] + beta[t];
    out[b * DDIM + t + 512] = d1 * rstd * gamma[t + 512] + beta[t + 512];
}

extern "C" void kernel_launch(void* const* d_in, const int* in_sizes, int n_in,
                              void* d_out, int out_size, void* d_ws, size_t ws_size,
                              hipStream_t stream) {
    const float* query = (const float*)d_in[0];
    const float* ctx   = (const float*)d_in[1];
    const float* dist  = (const float*)d_in[2];
    const int*   mask  = (const int*)d_in[3];
    const float* Wq = (const float*)d_in[4];
    const float* bq = (const float*)d_in[5];
    const float* Wk = (const float*)d_in[6];
    const float* bk = (const float*)d_in[7];
    const float* Wv = (const float*)d_in[8];
    const float* bv = (const float*)d_in[9];
    const float* Wo = (const float*)d_in[10];
    const float* bo = (const float*)d_in[11];
    const float* gamma = (const float*)d_in[12];
    const float* beta  = (const float*)d_in[13];
    float* out = (float*)d_out;

    int B = in_sizes[0] / DDIM;        // 32
    int N = in_sizes[1] / (B * DDIM);  // 4096

    float* ws = (float*)d_ws;
    float* q      = ws;                                   // B*D
    float* qp     = q + (size_t)B * DDIM;                 // B*H*D
    float* sb     = qp + (size_t)B * NH * DDIM;           // B*H
    float* partA  = sb + (size_t)B * NH;                  // B*NS*H*D
    float* partM  = partA + (size_t)B * NS * NH * DDIM;   // B*NS*H
    float* partL  = partM + (size_t)B * NS * NH;          // B*NS*H
    float* ctxa   = partL + (size_t)B * NS * NH;          // B*H*D

    k_q<<<dim3(B, 8), 512, 0, stream>>>(query, Wq, bq, q);
    k_qp<<<dim3(B, DDIM / 16), 256, 0, stream>>>(q, Wk, qp);
    k_sb<<<1, B * NH, 0, stream>>>(q, bk, sb);
    k_flash<<<dim3(B, NS), 512, 0, stream>>>(ctx, qp, sb, dist, mask,
                                             partA, partM, partL, N);
    k_comb<<<B * NH, 256, 0, stream>>>(partA, partM, partL, ctxa);
    k_epi<<<B, 512, 0, stream>>>(ctxa, Wv, bv, Wo, bo, query, gamma, beta, out);
}